// Round 5
// baseline (129.623 us; speedup 1.0000x reference)
//
#include <hip/hip_runtime.h>
#include <hip/hip_bf16.h>
#include <stdint.h>

// VectorQuantizer: z_e (64,64,64,64) fp32, codebook (512,64) fp32.
// out = [z_q 16777216 floats][codebook_loss][commitment_loss]
//
// v10: CLEAN occupancy test. v9 post-mortem: MfmaUtil 15% == exact matrix-
// pipe work, VALU 23% == exact VALU work; ~65% of cycles are stall with only
// 2 waves/SIMD to hide them. v7 "tested" 4 waves/SIMD but bundled 3
// regressions (per-block fp32 cb re-read+pack on critical path, NT stores,
// structure change) -- not a valid test. v10 changes ONE variable vs v9:
// 512-thr blocks x 1 slab of 512 rows x 512 blocks. Fill-per-row identical
// (64KB prepacked per 512 rows), per-thread P1/P2 identical, P4' gathers
// identical (32 ds_read + 16 dense-1KB wave stores). Residency: 2 blocks/CU
// x 8 waves = 4 waves/SIMD (LDS 2x65KB=130<=160KB, VGPR ~96<=128).
// If neutral again => latency-hiding dead, floor is mixed R/W HBM stream;
// pivot to stream shaping. Kept: bf16 codebook in XOR-swizzled LDS, prep
// kernel -> prepacked ws, dot-only argmax bit-trick, serial fmax, ks-
// transposed P4', loss block-reduce + 2 scaled atomicAdds.

typedef __bf16 bf16x8 __attribute__((ext_vector_type(8)));
typedef float f32x16 __attribute__((ext_vector_type(16)));

union ABu { uint32_t w[4]; uint4 u4; bf16x8 v; };

__device__ inline uint32_t pack_bf16(float a, float b) {
  __hip_bfloat162 h = __float22bfloat162_rn(make_float2(a, b));
  uint32_t u;
  __builtin_memcpy(&u, &h, 4);
  return u;
}

// ---- prep: codebook fp32 -> bf16 (packed u32) + e2[k]
__global__ __launch_bounds__(256)
void vq_prep(const float* __restrict__ cb, uint32_t* __restrict__ cb_bf,
             float* __restrict__ e2) {
  int t = blockIdx.x * 256 + threadIdx.x;  // 0..16383, one u32 of cb_bf
  float2 f = ((const float2*)cb)[t];
  uint32_t u = pack_bf16(f.x, f.y);
  cb_bf[t] = u;
  __hip_bfloat162 h;
  __builtin_memcpy(&h, &u, 4);
  float2 fb = __bfloat1622float2(h);
  float s = fb.x * fb.x + fb.y * fb.y;
#pragma unroll
  for (int off = 1; off <= 16; off <<= 1) s += __shfl_xor(s, off);
  if ((t & 31) == 0) e2[t >> 5] = s;  // code = t>>5
}

// ---- main: 512 blocks x 512 threads; wave = 64 rows (2 x 32-row C tiles),
// block = one 512-row slab. Codebook in LDS (XOR swizzle), prepacked.
__global__ __launch_bounds__(512)
void vq_main(const float* __restrict__ zin, const uint32_t* __restrict__ cb_bf,
             const float* __restrict__ e2g, float* __restrict__ out) {
  // cbl dword addr for (code k, 16B chunk c): k*32 + ((c ^ (k&7)) << 2)
  __shared__ uint32_t cbl[16384];  // exactly 64 KB
  __shared__ unsigned short ks[512] __attribute__((aligned(16)));
  const int tid = threadIdx.x;
  const int wid = tid >> 6;    // 0..7
  const int lane = tid & 63;
  const int col = lane & 31;   // C col = z row within 32-tile
  const int half = lane >> 5;  // k-half for A/B frags
  const int xk = col & 7;      // XOR key for this lane's A codes

  // fill LDS codebook (swizzled), 8 x b128 per thread (prepacked bf16 ws)
  {
    const uint4* cb4 = (const uint4*)cb_bf;  // 4096 uint4
#pragma unroll
    for (int j = 0; j < 8; ++j) {
      int g = j * 512 + tid;
      int k = g >> 3, c = g & 7;
      *(uint4*)&cbl[k * 32 + ((c ^ (k & 7)) << 2)] = cb4[g];
    }
  }
  __syncthreads();

  const int s = blockIdx.x;  // one 512-row slab per block
  const int b = s >> 3;
  const int hw0 = (s & 7) << 9;
  const float* slab = zin + ((size_t)b << 18) + hw0;

  // P1: B-frags from global (dense lines) + z^2 partials
  ABu Bf[2][4];
  float z2[2];
#pragma unroll
  for (int rt = 0; rt < 2; ++rt) {
    const int r = wid * 64 + rt * 32 + col;
    float sacc = 0.f;
#pragma unroll
    for (int m = 0; m < 4; ++m) {
      const int d0 = m * 16 + half * 8;
#pragma unroll
      for (int p = 0; p < 4; ++p) {
        float va = slab[(size_t)(d0 + 2 * p) * 4096 + r];
        float vb = slab[(size_t)(d0 + 2 * p + 1) * 4096 + r];
        sacc += va * va + vb * vb;
        Bf[rt][m].w[p] = pack_bf16(va, vb);
      }
    }
    z2[rt] = sacc;
  }

  // P2: 16 code-tiles; A-frags from LDS (conflict-free b128), dbuf
  ABu A[4], An[4];
#pragma unroll
  for (int m = 0; m < 4; ++m)
    A[m].u4 = *(const uint4*)&cbl[(col << 5) + (((2 * m + half) ^ xk) << 2)];
  float st[2] = {-3.4e38f, -3.4e38f};
#pragma unroll 1
  for (int ct = 0; ct < 16; ++ct) {
    const int ctn = (ct + 1) & 15;
    const int nbase = (ctn << 10) + (col << 5);  // (ctn*32+col)*32 dwords
#pragma unroll
    for (int m = 0; m < 4; ++m)
      An[m].u4 = *(const uint4*)&cbl[nbase + (((2 * m + half) ^ xk) << 2)];
    const uint32_t ctor = (uint32_t)(ct << 5) | (uint32_t)(half << 2);
#pragma unroll
    for (int rt = 0; rt < 2; ++rt) {
      f32x16 acc = {0, 0, 0, 0, 0, 0, 0, 0, 0, 0, 0, 0, 0, 0, 0, 0};
#pragma unroll
      for (int m = 0; m < 4; ++m)
        acc = __builtin_amdgcn_mfma_f32_32x32x16_bf16(A[m].v, Bf[rt][m].v, acc, 0, 0, 0);
#pragma unroll
      for (int r16 = 0; r16 < 16; ++r16) {
        const uint32_t cr = (uint32_t)((r16 & 3) | ((r16 >> 2) << 3));
        uint32_t bits =
            (__builtin_bit_cast(uint32_t, acc[r16]) & 0xFFFFFE00u) | (ctor | cr);
        st[rt] = fmaxf(st[rt], __builtin_bit_cast(float, bits));
      }
    }
#pragma unroll
    for (int m = 0; m < 4; ++m) A[m].u4 = An[m].u4;
  }

  // P3: combine halves, decode k, loss; stash codes for transposed P4'
  float blk = 0.f;
  {
    float lsum = 0.f;
    int kk[2];
#pragma unroll
    for (int rt = 0; rt < 2; ++rt) {
      float mx = fmaxf(st[rt], __shfl_xor(st[rt], 32));
      float z2t = z2[rt] + __shfl_xor(z2[rt], 32);
      uint32_t mbits = __builtin_bit_cast(uint32_t, mx);
      kk[rt] = (int)(mbits & 511u);
      float dot = __builtin_bit_cast(float, mbits & 0xFFFFFE00u);
      lsum += z2t - 2.f * dot + e2g[kk[rt]];
    }
#pragma unroll
    for (int off = 1; off <= 16; off <<= 1) lsum += __shfl_xor(lsum, off);
    blk = lsum;
    if (half == 0) {
      ks[wid * 64 + col] = (unsigned short)kk[0];
      ks[wid * 64 + 32 + col] = (unsigned short)kk[1];
    }
  }
  __syncthreads();  // ks visible to all waves

  // P4': plane-contiguous dequant stores. Wave wid owns d = wid*8..wid*8+7
  // (4 even/odd pairs; c = d>>3 = wid, jj = (d>>1)&3 = i). Thread stores
  // rows 4*lane..+3 (lower 256) and 256+4*lane..+3 (upper 256): each wave
  // store-instr covers a dense 1KB run. Values via 32 ds_read_b32 gathers.
  {
    float* oslab = out + ((size_t)b << 18) + hw0;
    const int r0 = lane << 2;  // 0..252 step 4
    const uint2 kpA = *(const uint2*)&ks[r0];
    const uint2 kpB = *(const uint2*)&ks[256 + r0];
    int ka[4], kb[4];
    ka[0] = (int)(kpA.x & 0xFFFFu); ka[1] = (int)(kpA.x >> 16);
    ka[2] = (int)(kpA.y & 0xFFFFu); ka[3] = (int)(kpA.y >> 16);
    kb[0] = (int)(kpB.x & 0xFFFFu); kb[1] = (int)(kpB.x >> 16);
    kb[2] = (int)(kpB.y & 0xFFFFu); kb[3] = (int)(kpB.y >> 16);
#pragma unroll
    for (int i = 0; i < 4; ++i) {
      const int d = wid * 8 + 2 * i;  // even plane; pair (d, d+1)
      uint32_t wa[4], wb[4];
#pragma unroll
      for (int j = 0; j < 4; ++j) {
        wa[j] = cbl[(ka[j] << 5) + (((wid ^ (ka[j] & 7)) << 2) + i)];
        wb[j] = cbl[(kb[j] << 5) + (((wid ^ (kb[j] & 7)) << 2) + i)];
      }
      float4 v;
      // lower 256 rows, even plane d
      v.x = __builtin_bit_cast(float, wa[0] << 16);
      v.y = __builtin_bit_cast(float, wa[1] << 16);
      v.z = __builtin_bit_cast(float, wa[2] << 16);
      v.w = __builtin_bit_cast(float, wa[3] << 16);
      *(float4*)&oslab[(size_t)d * 4096 + r0] = v;
      // upper 256 rows, even plane d
      v.x = __builtin_bit_cast(float, wb[0] << 16);
      v.y = __builtin_bit_cast(float, wb[1] << 16);
      v.z = __builtin_bit_cast(float, wb[2] << 16);
      v.w = __builtin_bit_cast(float, wb[3] << 16);
      *(float4*)&oslab[(size_t)d * 4096 + 256 + r0] = v;
      // lower 256 rows, odd plane d+1
      v.x = __builtin_bit_cast(float, wa[0] & 0xFFFF0000u);
      v.y = __builtin_bit_cast(float, wa[1] & 0xFFFF0000u);
      v.z = __builtin_bit_cast(float, wa[2] & 0xFFFF0000u);
      v.w = __builtin_bit_cast(float, wa[3] & 0xFFFF0000u);
      *(float4*)&oslab[(size_t)(d + 1) * 4096 + r0] = v;
      // upper 256 rows, odd plane d+1
      v.x = __builtin_bit_cast(float, wb[0] & 0xFFFF0000u);
      v.y = __builtin_bit_cast(float, wb[1] & 0xFFFF0000u);
      v.z = __builtin_bit_cast(float, wb[2] & 0xFFFF0000u);
      v.w = __builtin_bit_cast(float, wb[3] & 0xFFFF0000u);
      *(float4*)&oslab[(size_t)(d + 1) * 4096 + 256 + r0] = v;
    }
  }

  // block loss reduce: reuse cbl after all LDS codebook reads are done
  __syncthreads();
  if (lane == 0) ((float*)cbl)[wid] = blk;
  __syncthreads();
  if (tid == 0) {
    float t = 0.f;
#pragma unroll
    for (int w = 0; w < 8; ++w) t += ((float*)cbl)[w];
    float sc = t * (1.0f / 16777216.0f);
    atomicAdd(out + 16777216, sc);
    atomicAdd(out + 16777217, 0.25f * sc);
  }
}

extern "C" void kernel_launch(void* const* d_in, const int* in_sizes, int n_in,
                              void* d_out, int out_size, void* d_ws, size_t ws_size,
                              hipStream_t stream) {
  const float* zin = (const float*)d_in[0];
  const float* cbf = (const float*)d_in[1];
  uint32_t* cb_bf = (uint32_t*)d_ws;                 // 64 KB bf16 codebook
  float* e2 = (float*)((char*)d_ws + 65536);         // 2 KB
  float* out = (float*)d_out;

  vq_prep<<<64, 256, 0, stream>>>(cbf, cb_bf, e2);
  vq_main<<<512, 512, 0, stream>>>(zin, cb_bf, e2, out);
}